// Round 3
// baseline (346.172 us; speedup 1.0000x reference)
//
#include <hip/hip_runtime.h>
#include <hip/hip_bf16.h>
#include <math.h>

// Problem constants
#define BB 4096
#define DD 2048
#define HH 2048

typedef __bf16 bf16x8 __attribute__((ext_vector_type(8)));
typedef float f32x4 __attribute__((ext_vector_type(4)));

__device__ __forceinline__ void async16(const void* g, void* l) {
  __builtin_amdgcn_global_load_lds(
      (const __attribute__((address_space(1))) unsigned int*)g,
      (__attribute__((address_space(3))) unsigned int*)l,
      16, 0, 0);
}

template <int N>
__device__ __forceinline__ void wait_vmcnt() {
  asm volatile("s_waitcnt vmcnt(%0)" ::"n"(N) : "memory");
}

__device__ __forceinline__ float sigmoidf_(float x) {
  return 1.0f / (1.0f + __expf(-x));
}
__device__ __forceinline__ float tanhf_(float x) {
  float t = __expf(-2.0f * fabsf(x));
  return copysignf((1.0f - t) / (1.0f + t), x);
}

__device__ __forceinline__ void store_bf8(__hip_bfloat16* dst, const float* v) {
  union { __hip_bfloat16 b[8]; uint4 u; } p;
#pragma unroll
  for (int e = 0; e < 8; e++) p.b[e] = __float2bfloat16(v[e]);
  *(uint4*)dst = p.u;
}

// ---------------------------------------------------------------------------
// bias[g][c] = b_g[c] + rb_g[c],  g in {z,i,f,o}
__global__ void prep_bias(const float* __restrict__ bz, const float* __restrict__ bi,
                          const float* __restrict__ bf, const float* __restrict__ bo,
                          const float* __restrict__ rbz, const float* __restrict__ rbi,
                          const float* __restrict__ rbf, const float* __restrict__ rbo,
                          float* __restrict__ bias) {
  int i = blockIdx.x * 256 + threadIdx.x;
  if (i < 2048) {
    bias[0 * 2048 + i] = bz[i] + rbz[i];
    bias[1 * 2048 + i] = bi[i] + rbi[i];
    bias[2 * 2048 + i] = bf[i] + rbf[i];
    bias[3 * 2048 + i] = bo[i] + rbo[i];
  }
}

// ---------------------------------------------------------------------------
// WT2 granule ((gn*16 + jt)*32 + ks)*128 + j*4 + pc  (16B granules), holding
// W/R[n][ks*32 + c*8 .. +8][jt*32+j] bf16x8, c = pc ^ ((j>>1)&3).
__global__ __launch_bounds__(256) void prep_w(
    const float* __restrict__ Wz, const float* __restrict__ Wi,
    const float* __restrict__ Wf, const float* __restrict__ Wo,
    const float* __restrict__ Rz, const float* __restrict__ Ri,
    const float* __restrict__ Rf, const float* __restrict__ Ro,
    __hip_bfloat16* __restrict__ WT2) {
  const int jt = blockIdx.x;    // 16 j-tiles of 32
  const int ksg = blockIdx.y;   // 8 groups of 128 k
  const int gn = blockIdx.z;    // g*4 + n
  const int g = gn >> 2, nn = gn & 3;
  const float* src;
  if (ksg < 4) src = (g == 0 ? Wz : g == 1 ? Wi : g == 2 ? Wf : Wo);
  else         src = (g == 0 ? Rz : g == 1 ? Ri : g == 2 ? Rf : Ro);
  const int t = threadIdx.x;
#pragma unroll
  for (int q = 0; q < 2; q++) {
    int u = t + q * 256;
    int ksl = u >> 7, j = (u >> 2) & 31, pc = u & 3;
    int c = pc ^ ((j >> 1) & 3);
    int kr = (ksg & 3) * 128 + ksl * 32 + c * 8;
    const float* s0 = src + ((size_t)nn * 512 + kr) * 512 + jt * 32 + j;
    float v[8];
#pragma unroll
    for (int e = 0; e < 8; e++) v[e] = s0[(size_t)e * 512];
    size_t gr = ((size_t)(gn * 16 + jt) * 32 + ksg * 4 + ksl) * 128 + j * 4 + pc;
    store_bf8(WT2 + gr * 8, v);
  }
}

// ---------------------------------------------------------------------------
// Per row: LN -> conv3 -> SiLU. Emits tiled+swizzled bf16 (unchanged layout).
//  xh2 granule ((mb*4+n)*32 + ks)*512 + rl*4 + pc : ks<16 = x, ks>=16 = h
//  xc2 granule ((mb*4+n)*16 + ks)*512 + rl*4 + pc : SiLU(conv(LN(x)))
__global__ __launch_bounds__(256) void prep_act(
    const float* __restrict__ x, const float* __restrict__ h,
    const float* __restrict__ lg, const float* __restrict__ lb,
    const float* __restrict__ cw, const float* __restrict__ cb,
    __hip_bfloat16* __restrict__ xh2, __hip_bfloat16* __restrict__ xc2) {
  const int r = blockIdx.x, t = threadIdx.x, l = t & 63;
  const int mb = r >> 7, rl = r & 127, swz = (rl >> 1) & 3;
  const int n = t >> 6, ktl = (t >> 2) & 15, pc = (t & 3) ^ swz;
  __shared__ float red[8];
  __shared__ float edge[256][2];
  const float* xr = x + (size_t)r * 2048;
  const float* hr = h + (size_t)r * 2048;
  float4 v0 = ((const float4*)xr)[t * 2];
  float4 v1 = ((const float4*)xr)[t * 2 + 1];
  float vv[8] = {v0.x, v0.y, v0.z, v0.w, v1.x, v1.y, v1.z, v1.w};
  float s = 0.f, s2 = 0.f;
#pragma unroll
  for (int e = 0; e < 8; e++) { s += vv[e]; s2 += vv[e] * vv[e]; }
#pragma unroll
  for (int off = 32; off > 0; off >>= 1) {
    s += __shfl_down(s, off);
    s2 += __shfl_down(s2, off);
  }
  const int w = t >> 6;
  if (l == 0) { red[w] = s; red[4 + w] = s2; }
  __syncthreads();
  const float mu = (red[0] + red[1] + red[2] + red[3]) * (1.0f / 2048.0f);
  const float var = (red[4] + red[5] + red[6] + red[7]) * (1.0f / 2048.0f) - mu * mu;
  const float rs = rsqrtf(var + 1e-5f);

  float4 h0 = ((const float4*)hr)[t * 2];
  float4 h1 = ((const float4*)hr)[t * 2 + 1];
  float hh[8] = {h0.x, h0.y, h0.z, h0.w, h1.x, h1.y, h1.z, h1.w};
  float4 g0 = ((const float4*)lg)[t * 2], g1 = ((const float4*)lg)[t * 2 + 1];
  float4 b0 = ((const float4*)lb)[t * 2], b1 = ((const float4*)lb)[t * 2 + 1];
  float gg[8] = {g0.x, g0.y, g0.z, g0.w, g1.x, g1.y, g1.z, g1.w};
  float bb[8] = {b0.x, b0.y, b0.z, b0.w, b1.x, b1.y, b1.z, b1.w};
  float fr[8];
#pragma unroll
  for (int e = 0; e < 8; e++) fr[e] = (vv[e] - mu) * rs * gg[e] + bb[e];

  const size_t bx = ((size_t)(mb * 4 + n) * 32 + ktl) * 512 + rl * 4 + pc;
  const size_t bh = ((size_t)(mb * 4 + n) * 32 + 16 + ktl) * 512 + rl * 4 + pc;
  store_bf8(xh2 + bx * 8, vv);
  store_bf8(xh2 + bh * 8, hh);

  edge[t][0] = fr[6]; edge[t][1] = fr[7];
  __syncthreads();
  float p6 = __shfl_up(fr[6], 1);
  float p7 = __shfl_up(fr[7], 1);
  if (l == 0) {
    p6 = (t > 0) ? edge[t - 1][0] : 0.f;
    p7 = (t > 0) ? edge[t - 1][1] : 0.f;
  }
  const float w0 = cw[0], w1 = cw[1], w2 = cw[2], cbv = cb[0];
  float sc[8];
  {
    float xc0 = w0 * p6 + w1 * p7 + w2 * fr[0] + cbv;
    float xc1 = w0 * p7 + w1 * fr[0] + w2 * fr[1] + cbv;
    sc[0] = xc0 * sigmoidf_(xc0);
    sc[1] = xc1 * sigmoidf_(xc1);
  }
#pragma unroll
  for (int e = 2; e < 8; e++) {
    float xc = w0 * fr[e - 2] + w1 * fr[e - 1] + w2 * fr[e] + cbv;
    sc[e] = xc * sigmoidf_(xc);
  }
  const size_t bc = ((size_t)(mb * 4 + n) * 16 + ktl) * 512 + rl * 4 + pc;
  store_bf8(xc2 + bc * 8, sc);
}

// ---------------------------------------------------------------------------
// Fused 4-gate block GEMM + sLSTM epilogue — B-in-LDS ring, A direct-to-reg.
//
// Grid 1024 (XCD-swizzled), 512 threads = 8 waves, 64 KiB STATIC LDS.
// K = 32 halves of 32 k. Per half h, per wave:
//   * 4 ds_read_b128 B-frags (g0,g1 x sj0,sj1) from ring slot h&3
//   * 4 global_load_dwordx4: A-frags for half h+1 -> VGPRs (compiler-tracked
//     vmcnt dep; jhalf-twin waves read identical lines -> L1 broadcast;
//     pair 1 reads xc2 directly for h<16 — no C staging at all)
//   * 2 global_load_lds: stage B(h+3) into ring slot (h+3)&3
//   * setprio(1) 16x MFMA setprio(0)
//   * s_waitcnt vmcnt(8): 12 vm-ops are issued after B(h+1)'s 2 loads, so
//     vmcnt(8) guarantees B(h+1) is in LDS while keeping 8 loads in flight
//     (never drains to 0); then raw s_barrier publishes the slot.
// LDS pipe/CU: reads 49k cyc + stage-writes 16k << old 131k; MFMA floor 33us.
__global__ __launch_bounds__(512, 2) void gemm_fused(
    const __hip_bfloat16* __restrict__ xh2, const __hip_bfloat16* __restrict__ xc2,
    const __hip_bfloat16* __restrict__ WT2, const float* __restrict__ bias,
    const float* __restrict__ c_prev, float* __restrict__ out) {
  // [0,64K) B ring: 4 slots x 16K; slot layout [4g][2jh][2048B = 2sj x 1024]
  // epilogue union: zo bf16 [2][128][72] = 36,864B
  __shared__ __attribute__((aligned(16))) char smem[65536];
  __hip_bfloat16* zo = (__hip_bfloat16*)smem;

  // XCD swizzle: per XCD concurrent window = 1 n x 4 jt x 8 mb
  const int o = blockIdx.x;
  const int xcd = o & 7, sfx = o >> 3;
  const int n = xcd >> 1;
  const int jt = (xcd & 1) * 4 + (sfx & 3);
  const int mb = sfx >> 2;

  const int t = threadIdx.x, w = t >> 6, l = t & 63;
  const int pair = w >> 2, mhalf = (w >> 1) & 1, jhalf = w & 1;
  const int lj = l & 15;

  // frag byte offset (swizzled): row lj -> lj*64 + (chunk ^ ((lj>>1)&3))*16
  const int fo = lj * 64 + (((l >> 4) ^ ((lj >> 1) & 3)) * 16);
  const int g0 = pair ? 1 : 0, g1 = pair ? 2 : 3;

  // A sources (direct global->reg). Per half h: base + h*8192 (+s*1024).
  const char* gAx = (const char*)xh2 + (size_t)(mb * 4 + n) * 262144 + mhalf * 4096 + fo;
  const char* gAc = (const char*)xc2 + (size_t)(mb * 4 + n) * 131072 + mhalf * 4096 + fo;

  // B staging: 512 thr x 2 async16 = 1024 granules = 16K per half.
  const int u0 = t, u1 = t + 512;
  const int bg0 = u0 >> 8, bj0 = (u0 >> 7) & 1, br0 = u0 & 127;
  const int bg1 = u1 >> 8, bj1 = (u1 >> 7) & 1, br1 = u1 & 127;
  const char* gB0 = (const char*)WT2 +
      ((size_t)((bg0 * 4 + n) * 16 + jt * 2 + bj0)) * 65536 + br0 * 16;
  const char* gB1 = (const char*)WT2 +
      ((size_t)((bg1 * 4 + n) * 16 + jt * 2 + bj1)) * 65536 + br1 * 16;
  const int dB0 = bg0 * 4096 + bj0 * 2048 + br0 * 16;
  const int dB1 = bg1 * 4096 + bj1 * 2048 + br1 * 16;

  f32x4 acc[4][2][2] = {};
  bf16x8 afa0, afa1, afa2, afa3, afb0, afb1, afb2, afb3;

#define BAR() __builtin_amdgcn_s_barrier()
#define SBZ() __builtin_amdgcn_sched_barrier(0)

#define APTR(h) ((((h) < 16) && pair) ? (gAc + (size_t)(h) * 8192) \
                                      : (gAx + (size_t)(h) * 8192))

#define LOADA(h, X)                                                            \
  do { if ((h) < 32) {                                                         \
    const char* ap_ = APTR(h);                                                 \
    af##X##0 = *(const bf16x8*)(ap_);                                          \
    af##X##1 = *(const bf16x8*)(ap_ + 1024);                                   \
    af##X##2 = *(const bf16x8*)(ap_ + 2048);                                   \
    af##X##3 = *(const bf16x8*)(ap_ + 3072);                                   \
  } } while (0)

#define STAGEB(h)                                                              \
  do { if ((h) < 32) {                                                         \
    char* d_ = smem + ((h) & 3) * 16384;                                       \
    async16(gB0 + (size_t)(h) * 2048, d_ + dB0);                               \
    async16(gB1 + (size_t)(h) * 2048, d_ + dB1);                               \
  } } while (0)

#define MFMA8(C, sj, B0, B1)                                                   \
  do {                                                                         \
    acc[0][sj][0] = __builtin_amdgcn_mfma_f32_16x16x32_bf16(af##C##0, B0, acc[0][sj][0], 0, 0, 0); \
    acc[1][sj][0] = __builtin_amdgcn_mfma_f32_16x16x32_bf16(af##C##1, B0, acc[1][sj][0], 0, 0, 0); \
    acc[2][sj][0] = __builtin_amdgcn_mfma_f32_16x16x32_bf16(af##C##2, B0, acc[2][sj][0], 0, 0, 0); \
    acc[3][sj][0] = __builtin_amdgcn_mfma_f32_16x16x32_bf16(af##C##3, B0, acc[3][sj][0], 0, 0, 0); \
    acc[0][sj][1] = __builtin_amdgcn_mfma_f32_16x16x32_bf16(af##C##0, B1, acc[0][sj][1], 0, 0, 0); \
    acc[1][sj][1] = __builtin_amdgcn_mfma_f32_16x16x32_bf16(af##C##1, B1, acc[1][sj][1], 0, 0, 0); \
    acc[2][sj][1] = __builtin_amdgcn_mfma_f32_16x16x32_bf16(af##C##2, B1, acc[2][sj][1], 0, 0, 0); \
    acc[3][sj][1] = __builtin_amdgcn_mfma_f32_16x16x32_bf16(af##C##3, B1, acc[3][sj][1], 0, 0, 0); \
  } while (0)

  // HALF(h): consumes af{C} (A(h)) + LDS B(h); loads af{X} <- A(h+1);
  // stages B(h+3); counted wait + barrier publishes slot (h+1)&3.
#define HALF(h, C, X)                                                          \
  do {                                                                         \
    const char* Bb_ = smem + ((h) & 3) * 16384 + jhalf * 2048 + fo;            \
    bf16x8 b00 = *(const bf16x8*)(Bb_ + g0 * 4096);                            \
    bf16x8 b10 = *(const bf16x8*)(Bb_ + g1 * 4096);                            \
    bf16x8 b01 = *(const bf16x8*)(Bb_ + g0 * 4096 + 1024);                     \
    bf16x8 b11 = *(const bf16x8*)(Bb_ + g1 * 4096 + 1024);                     \
    LOADA((h) + 1, X);                                                         \
    STAGEB((h) + 3);                                                           \
    SBZ();                                                                     \
    __builtin_amdgcn_s_setprio(1);                                             \
    MFMA8(C, 0, b00, b10);                                                     \
    MFMA8(C, 1, b01, b11);                                                     \
    __builtin_amdgcn_s_setprio(0);                                             \
    SBZ();                                                                     \
    if ((h) < 31) {                                                            \
      wait_vmcnt<8>();                                                         \
      BAR(); SBZ();                                                            \
    }                                                                          \
  } while (0)

  // prologue: A(0) first (so later waits don't force it last), then B(0..2)
  LOADA(0, a);
  STAGEB(0);
  STAGEB(1);
  STAGEB(2);
  wait_vmcnt<4>();  // forces A(0)+B(0); B(1),B(2) stay in flight
  BAR(); SBZ();

  HALF(0, a, b);  HALF(1, b, a);  HALF(2, a, b);  HALF(3, b, a);
  HALF(4, a, b);  HALF(5, b, a);  HALF(6, a, b);  HALF(7, b, a);
  HALF(8, a, b);  HALF(9, b, a);  HALF(10, a, b); HALF(11, b, a);
  HALF(12, a, b); HALF(13, b, a); HALF(14, a, b); HALF(15, b, a);
  HALF(16, a, b); HALF(17, b, a); HALF(18, a, b); HALF(19, b, a);
  HALF(20, a, b); HALF(21, b, a); HALF(22, a, b); HALF(23, b, a);
  HALF(24, a, b); HALF(25, b, a); HALF(26, a, b); HALF(27, b, a);
  HALF(28, a, b); HALF(29, b, a); HALF(30, a, b); HALF(31, b, a);

  // ---- Epilogue. C/D 16x16: col = lane&15, row = (lane>>4)*4 + reg.
  const int r0 = (l >> 4) * 4;
  const int colb = n * 512 + jt * 64;
  __syncthreads();
  if (pair == 0) {
#pragma unroll
    for (int sj = 0; sj < 2; ++sj) {
      const int jc = jhalf * 32 + sj * 16 + lj;
      const float bz_ = bias[colb + jc];
      const float bo_ = bias[3 * 2048 + colb + jc];
#pragma unroll
      for (int s = 0; s < 4; ++s) {
#pragma unroll
        for (int rr = 0; rr < 4; ++rr) {
          const int rl = mhalf * 64 + s * 16 + r0 + rr;
          zo[rl * 72 + jc] = __float2bfloat16(tanhf_(acc[s][sj][0][rr] + bz_));
          zo[(128 + rl) * 72 + jc] = __float2bfloat16(sigmoidf_(acc[s][sj][1][rr] + bo_));
        }
      }
    }
  }
  __syncthreads();
  if (pair == 1) {
    const size_t HC = (size_t)BB * HH;
#pragma unroll
    for (int sj = 0; sj < 2; ++sj) {
      const int jc = jhalf * 32 + sj * 16 + lj;
      const int col = colb + jc;
      const float bi_ = bias[1 * 2048 + col];
      const float bf_ = bias[2 * 2048 + col];
#pragma unroll
      for (int s = 0; s < 4; ++s) {
#pragma unroll
        for (int rr = 0; rr < 4; ++rr) {
          const int rl = mhalf * 64 + s * 16 + r0 + rr;
          const int row = mb * 128 + rl;
          const float z  = __bfloat162float(zo[rl * 72 + jc]);
          const float og = __bfloat162float(zo[(128 + rl) * 72 + jc]);
          const float ig = sigmoidf_(acc[s][sj][0][rr] + bi_);
          const float fg = sigmoidf_(acc[s][sj][1][rr] + bf_);
          const float cp = c_prev[(size_t)row * 2048 + col];
          const float c = fg * cp + ig * z;
          const float hv = og * tanhf_(c);
          out[(size_t)row * 2048 + col] = hv;
          out[HC + (size_t)row * 2048 + col] = c;
        }
      }
    }
  }
}

// ---------------------------------------------------------------------------
extern "C" void kernel_launch(void* const* d_in, const int* in_sizes, int n_in,
                              void* d_out, int out_size, void* d_ws, size_t ws_size,
                              hipStream_t stream) {
  const float* x      = (const float*)d_in[0];
  const float* h_prev = (const float*)d_in[1];
  const float* c_prev = (const float*)d_in[2];
  const float* ln_g   = (const float*)d_in[3];
  const float* ln_b   = (const float*)d_in[4];
  const float* conv_w = (const float*)d_in[5];
  const float* conv_b = (const float*)d_in[6];
  const float* Wz = (const float*)d_in[7];
  const float* bz = (const float*)d_in[8];
  const float* Wi = (const float*)d_in[9];
  const float* bi = (const float*)d_in[10];
  const float* Wf = (const float*)d_in[11];
  const float* bf = (const float*)d_in[12];
  const float* Wo = (const float*)d_in[13];
  const float* bo = (const float*)d_in[14];
  const float* Rz = (const float*)d_in[15];
  const float* rbz = (const float*)d_in[16];
  const float* Ri = (const float*)d_in[17];
  const float* rbi = (const float*)d_in[18];
  const float* Rf = (const float*)d_in[19];
  const float* rbf = (const float*)d_in[20];
  const float* Ro = (const float*)d_in[21];
  const float* rbo = (const float*)d_in[22];
  float* out = (float*)d_out;

  char* ws = (char*)d_ws;
  __hip_bfloat16* xh2 = (__hip_bfloat16*)(ws);                       // 32 MiB
  __hip_bfloat16* xc2 = (__hip_bfloat16*)(ws + 33554432);            // 16 MiB
  __hip_bfloat16* WT2 = (__hip_bfloat16*)(ws + 33554432 + 16777216); // 16 MiB
  float* bias         = (float*)(ws + 33554432 + 2 * 16777216);      // 32 KiB

  prep_bias<<<8, 256, 0, stream>>>(bz, bi, bf, bo, rbz, rbi, rbf, rbo, bias);
  prep_w<<<dim3(16, 8, 16), 256, 0, stream>>>(Wz, Wi, Wf, Wo, Rz, Ri, Rf, Ro, WT2);
  prep_act<<<BB, 256, 0, stream>>>(x, h_prev, ln_g, ln_b, conv_w, conv_b, xh2, xc2);
  gemm_fused<<<1024, 512, 0, stream>>>(xh2, xc2, WT2, bias, c_prev, out);
}

// Round 4
// 321.768 us; speedup vs baseline: 1.0758x; 1.0758x over previous
//
#include <hip/hip_runtime.h>
#include <hip/hip_bf16.h>
#include <math.h>

// Problem constants
#define BB 4096
#define DD 2048
#define HH 2048

typedef __bf16 bf16x8 __attribute__((ext_vector_type(8)));
typedef float f32x4 __attribute__((ext_vector_type(4)));

__device__ __forceinline__ void async16(const void* g, void* l) {
  __builtin_amdgcn_global_load_lds(
      (const __attribute__((address_space(1))) unsigned int*)g,
      (__attribute__((address_space(3))) unsigned int*)l,
      16, 0, 0);
}

__device__ __forceinline__ float sigmoidf_(float x) {
  return 1.0f / (1.0f + __expf(-x));
}
__device__ __forceinline__ float tanhf_(float x) {
  float t = __expf(-2.0f * fabsf(x));
  return copysignf((1.0f - t) / (1.0f + t), x);
}

__device__ __forceinline__ void store_bf8(__hip_bfloat16* dst, const float* v) {
  union { __hip_bfloat16 b[8]; uint4 u; } p;
#pragma unroll
  for (int e = 0; e < 8; e++) p.b[e] = __float2bfloat16(v[e]);
  *(uint4*)dst = p.u;
}

// ---------------------------------------------------------------------------
// prep_all: one launch for all preprocessing (removes 2 launch gaps; lets the
// independent preps co-fill the GPU; and — diagnostically — the merged kernel
// exceeds gemm's dur so it surfaces in the top-5 with counters).
//   blocks [0, 4096)      : act  (LN -> conv3 -> SiLU + bf16 tiling), 1 row
//   blocks [4096, 6144)   : w    (W/R f32 -> swizzled bf16 WT2), LDS transpose
//   blocks [6144, 6152)   : bias (b + rb)
// Output layouts are byte-identical to the previous three kernels:
//  xh2 granule ((mb*4+n)*32 + ks)*512 + rl*4 + pc : ks<16 = x, ks>=16 = h
//  xc2 granule ((mb*4+n)*16 + ks)*512 + rl*4 + pc : SiLU(conv(LN(x)))
//  WT2 granule ((gn*16+jt)*32 + ks)*128 + j*4 + pc : W/R[n][k..k+8][j] bf16x8
__global__ __launch_bounds__(256) void prep_all(
    const float* __restrict__ x, const float* __restrict__ h,
    const float* __restrict__ lg, const float* __restrict__ lb,
    const float* __restrict__ cw, const float* __restrict__ cb,
    __hip_bfloat16* __restrict__ xh2, __hip_bfloat16* __restrict__ xc2,
    const float* __restrict__ Wz, const float* __restrict__ Wi,
    const float* __restrict__ Wf, const float* __restrict__ Wo,
    const float* __restrict__ Rz, const float* __restrict__ Ri,
    const float* __restrict__ Rf, const float* __restrict__ Ro,
    __hip_bfloat16* __restrict__ WT2,
    const float* __restrict__ bz, const float* __restrict__ bi,
    const float* __restrict__ bf, const float* __restrict__ bo,
    const float* __restrict__ rbz, const float* __restrict__ rbi,
    const float* __restrict__ rbf, const float* __restrict__ rbo,
    float* __restrict__ bias) {
  // shared: act uses [0,8) red + [8, 8+512) edge; w uses [128][33] f32 tile
  __shared__ float smf[4224];  // 16,896 B
  const int b = blockIdx.x, t = threadIdx.x;

  if (b < 4096) {
    // ---------------- act branch (identical math to prior prep_act) --------
    const int r = b, l = t & 63;
    const int mb = r >> 7, rl = r & 127, swz = (rl >> 1) & 3;
    const int n = t >> 6, ktl = (t >> 2) & 15, pc = (t & 3) ^ swz;
    float* red = smf;                         // [8]
    float* edge = smf + 8;                    // [256][2]
    const float* xr = x + (size_t)r * 2048;
    const float* hr = h + (size_t)r * 2048;
    float4 v0 = ((const float4*)xr)[t * 2];
    float4 v1 = ((const float4*)xr)[t * 2 + 1];
    float vv[8] = {v0.x, v0.y, v0.z, v0.w, v1.x, v1.y, v1.z, v1.w};
    float s = 0.f, s2 = 0.f;
#pragma unroll
    for (int e = 0; e < 8; e++) { s += vv[e]; s2 += vv[e] * vv[e]; }
#pragma unroll
    for (int off = 32; off > 0; off >>= 1) {
      s += __shfl_down(s, off);
      s2 += __shfl_down(s2, off);
    }
    const int w = t >> 6;
    if (l == 0) { red[w] = s; red[4 + w] = s2; }
    __syncthreads();
    const float mu = (red[0] + red[1] + red[2] + red[3]) * (1.0f / 2048.0f);
    const float var = (red[4] + red[5] + red[6] + red[7]) * (1.0f / 2048.0f) - mu * mu;
    const float rs = rsqrtf(var + 1e-5f);

    float4 h0 = ((const float4*)hr)[t * 2];
    float4 h1 = ((const float4*)hr)[t * 2 + 1];
    float hh[8] = {h0.x, h0.y, h0.z, h0.w, h1.x, h1.y, h1.z, h1.w};
    float4 g0 = ((const float4*)lg)[t * 2], g1 = ((const float4*)lg)[t * 2 + 1];
    float4 b0 = ((const float4*)lb)[t * 2], b1 = ((const float4*)lb)[t * 2 + 1];
    float gg[8] = {g0.x, g0.y, g0.z, g0.w, g1.x, g1.y, g1.z, g1.w};
    float bbv[8] = {b0.x, b0.y, b0.z, b0.w, b1.x, b1.y, b1.z, b1.w};
    float fr[8];
#pragma unroll
    for (int e = 0; e < 8; e++) fr[e] = (vv[e] - mu) * rs * gg[e] + bbv[e];

    const size_t bx = ((size_t)(mb * 4 + n) * 32 + ktl) * 512 + rl * 4 + pc;
    const size_t bh = ((size_t)(mb * 4 + n) * 32 + 16 + ktl) * 512 + rl * 4 + pc;
    store_bf8(xh2 + bx * 8, vv);
    store_bf8(xh2 + bh * 8, hh);

    edge[t * 2 + 0] = fr[6]; edge[t * 2 + 1] = fr[7];
    __syncthreads();
    float p6 = __shfl_up(fr[6], 1);
    float p7 = __shfl_up(fr[7], 1);
    if (l == 0) {
      p6 = (t > 0) ? edge[(t - 1) * 2 + 0] : 0.f;
      p7 = (t > 0) ? edge[(t - 1) * 2 + 1] : 0.f;
    }
    const float w0 = cw[0], w1 = cw[1], w2 = cw[2], cbv = cb[0];
    float sc[8];
    {
      float xc0 = w0 * p6 + w1 * p7 + w2 * fr[0] + cbv;
      float xc1 = w0 * p7 + w1 * fr[0] + w2 * fr[1] + cbv;
      sc[0] = xc0 * sigmoidf_(xc0);
      sc[1] = xc1 * sigmoidf_(xc1);
    }
#pragma unroll
    for (int e = 2; e < 8; e++) {
      float xc = w0 * fr[e - 2] + w1 * fr[e - 1] + w2 * fr[e] + cbv;
      sc[e] = xc * sigmoidf_(xc);
    }
    const size_t bc = ((size_t)(mb * 4 + n) * 16 + ktl) * 512 + rl * 4 + pc;
    store_bf8(xc2 + bc * 8, sc);

  } else if (b < 6144) {
    // ---------------- w branch: coalesced tile load -> LDS -> swizzled out -
    const int flat = b - 4096;
    const int jt = flat & 15;          // 16 j-tiles of 32
    const int ksg = (flat >> 4) & 7;   // 8 groups of 128 k
    const int gn = flat >> 7;          // g*4 + n
    const int g = gn >> 2, nn = gn & 3;
    const float* src;
    if (ksg < 4) src = (g == 0 ? Wz : g == 1 ? Wi : g == 2 ? Wf : Wo);
    else         src = (g == 0 ? Rz : g == 1 ? Ri : g == 2 ? Rf : Ro);
    const int kb = (ksg & 3) * 128;    // k-base of this 128-row tile

    // phase 1: load [128 rows][32 cols] f32, fully coalesced (128B/row chunk)
    {
      const int r8 = t >> 3, c4 = t & 7;
      const float* sp = src + ((size_t)nn * 512 + kb + r8) * 512 + jt * 32 + c4 * 4;
#pragma unroll
      for (int rr = 0; rr < 4; rr++) {
        float4 v = *(const float4*)(sp + (size_t)rr * 32 * 512);
        float* d = smf + (r8 + rr * 32) * 33 + c4 * 4;
        d[0] = v.x; d[1] = v.y; d[2] = v.z; d[3] = v.w;
      }
    }
    __syncthreads();
    // phase 2: identical output mapping as before, reads from LDS
#pragma unroll
    for (int q = 0; q < 2; q++) {
      int u = t + q * 256;
      int ksl = u >> 7, j = (u >> 2) & 31, pc = u & 3;
      int c = pc ^ ((j >> 1) & 3);
      int krl = ksl * 32 + c * 8;
      float v[8];
#pragma unroll
      for (int e = 0; e < 8; e++) v[e] = smf[(krl + e) * 33 + j];
      size_t gr = ((size_t)(gn * 16 + jt) * 32 + ksg * 4 + ksl) * 128 + j * 4 + pc;
      store_bf8(WT2 + gr * 8, v);
    }

  } else {
    // ---------------- bias branch -----------------------------------------
    int i = (b - 6144) * 256 + t;
    if (i < 2048) {
      bias[0 * 2048 + i] = bz[i] + rbz[i];
      bias[1 * 2048 + i] = bi[i] + rbi[i];
      bias[2 * 2048 + i] = bf[i] + rbf[i];
      bias[3 * 2048 + i] = bo[i] + rbo[i];
    }
  }
}

// ---------------------------------------------------------------------------
// Fused 4-gate block GEMM + sLSTM epilogue (reverted to the round-0 version,
// measured 129.9 us: BK=64, 2-phase, 64KB static LDS, 2 blocks/CU).
// Grid (32 mb, 8 jt, 4 n), 512 threads = 8 waves.
// Wave w: pair = w>>2 (0:(z,o), 1:(i,f)), mhalf = (w>>1)&1, jhalf = w&1.
__global__ __launch_bounds__(512, 4) void gemm_fused(
    const __hip_bfloat16* __restrict__ xh2, const __hip_bfloat16* __restrict__ xc2,
    const __hip_bfloat16* __restrict__ WT2, const float* __restrict__ bias,
    const float* __restrict__ c_prev, float* __restrict__ out) {
  // smem map: [0,16K) A=x/h  [2kh][128m][64B swz]
  //           [16K,32K) C=xc [2kh][128m][64B swz]
  //           [32K,64K) B    [4g][2jth][2kh][32j][64B swz]
  // union: zo bf16 [2][128][72] = 36,864B
  __shared__ __attribute__((aligned(16))) char smem[65536];
  __hip_bfloat16* zo = (__hip_bfloat16*)smem;

  const int mb = blockIdx.x, jt = blockIdx.y, n = blockIdx.z;
  const int t = threadIdx.x, w = t >> 6, l = t & 63;
  const int pair = w >> 2, mhalf = (w >> 1) & 1, jhalf = w & 1;
  const int lj = l & 15;

  // staging sources
  const char* pA = (const char*)xh2 + (size_t)(mb * 4 + n) * 262144 + t * 16;
  const char* pC = (const char*)xc2 + (size_t)(mb * 4 + n) * 131072 + t * 16;
  const char* pB = (const char*)WT2 +
      (size_t)(n * 16 + jt * 2 + ((t >> 8) & 1)) * 65536 + ((t >> 7) & 1) * 2048 + (t & 127) * 16;
  char* dA = smem + t * 16;
  char* dB = smem + 32768 + t * 16;

  // frag byte offset (swizzled): row lj -> lj*64 + (chunk ^ ((lj>>1)&3))*16
  const int fo = lj * 64 + (((l >> 4) ^ ((lj >> 1) & 3)) * 16);
  const int g0 = pair ? 1 : 0, g1 = pair ? 2 : 3;

  f32x4 acc[4][2][2] = {};

  for (int ks2 = 0; ks2 < 16; ++ks2) {
    __syncthreads();
    async16(pA, dA);
    async16(pA + 8192, dA + 8192);
    if (ks2 < 8) {
      async16(pC, dA + 16384);
      async16(pC + 8192, dA + 24576);
    }
    async16(pB, dB);
    async16(pB + 4194304, dB + 8192);
    async16(pB + 8388608, dB + 16384);
    async16(pB + 12582912, dB + 24576);
    pA += 16384; pC += 16384; pB += 4096;
    __syncthreads();

    const char* Ab = ((ks2 < 8 && pair) ? smem + 16384 : smem) + mhalf * 4096 + fo;
    const char* Bb = smem + 32768 + jhalf * 4096 + fo;
#pragma unroll
    for (int kh = 0; kh < 2; ++kh) {
      bf16x8 af[4];
#pragma unroll
      for (int s = 0; s < 4; ++s)
        af[s] = *(const bf16x8*)(Ab + kh * 8192 + s * 1024);
#pragma unroll
      for (int sj = 0; sj < 2; ++sj) {
        bf16x8 b0 = *(const bf16x8*)(Bb + g0 * 8192 + kh * 2048 + sj * 1024);
        bf16x8 b1 = *(const bf16x8*)(Bb + g1 * 8192 + kh * 2048 + sj * 1024);
#pragma unroll
        for (int s = 0; s < 4; ++s) {
          acc[s][sj][0] = __builtin_amdgcn_mfma_f32_16x16x32_bf16(af[s], b0, acc[s][sj][0], 0, 0, 0);
          acc[s][sj][1] = __builtin_amdgcn_mfma_f32_16x16x32_bf16(af[s], b1, acc[s][sj][1], 0, 0, 0);
        }
      }
    }
  }

  // ---- Epilogue. C/D 16x16: col = lane&15, row = (lane>>4)*4 + reg.
  const int r0 = (l >> 4) * 4;
  const int colb = n * 512 + jt * 64;
  __syncthreads();
  if (pair == 0) {
#pragma unroll
    for (int sj = 0; sj < 2; ++sj) {
      const int jc = jhalf * 32 + sj * 16 + lj;
      const float bz_ = bias[colb + jc];
      const float bo_ = bias[3 * 2048 + colb + jc];
#pragma unroll
      for (int s = 0; s < 4; ++s) {
#pragma unroll
        for (int rr = 0; rr < 4; ++rr) {
          const int rl = mhalf * 64 + s * 16 + r0 + rr;
          zo[rl * 72 + jc] = __float2bfloat16(tanhf_(acc[s][sj][0][rr] + bz_));
          zo[(128 + rl) * 72 + jc] = __float2bfloat16(sigmoidf_(acc[s][sj][1][rr] + bo_));
        }
      }
    }
  }
  __syncthreads();
  if (pair == 1) {
    const size_t HC = (size_t)BB * HH;
#pragma unroll
    for (int sj = 0; sj < 2; ++sj) {
      const int jc = jhalf * 32 + sj * 16 + lj;
      const int col = colb + jc;
      const float bi_ = bias[1 * 2048 + col];
      const float bf_ = bias[2 * 2048 + col];
#pragma unroll
      for (int s = 0; s < 4; ++s) {
#pragma unroll
        for (int rr = 0; rr < 4; ++rr) {
          const int rl = mhalf * 64 + s * 16 + r0 + rr;
          const int row = mb * 128 + rl;
          const float z  = __bfloat162float(zo[rl * 72 + jc]);
          const float og = __bfloat162float(zo[(128 + rl) * 72 + jc]);
          const float ig = sigmoidf_(acc[s][sj][0][rr] + bi_);
          const float fg = sigmoidf_(acc[s][sj][1][rr] + bf_);
          const float cp = c_prev[(size_t)row * 2048 + col];
          const float c = fg * cp + ig * z;
          const float hv = og * tanhf_(c);
          out[(size_t)row * 2048 + col] = hv;
          out[HC + (size_t)row * 2048 + col] = c;
        }
      }
    }
  }
}

// ---------------------------------------------------------------------------
extern "C" void kernel_launch(void* const* d_in, const int* in_sizes, int n_in,
                              void* d_out, int out_size, void* d_ws, size_t ws_size,
                              hipStream_t stream) {
  const float* x      = (const float*)d_in[0];
  const float* h_prev = (const float*)d_in[1];
  const float* c_prev = (const float*)d_in[2];
  const float* ln_g   = (const float*)d_in[3];
  const float* ln_b   = (const float*)d_in[4];
  const float* conv_w = (const float*)d_in[5];
  const float* conv_b = (const float*)d_in[6];
  const float* Wz = (const float*)d_in[7];
  const float* bz = (const float*)d_in[8];
  const float* Wi = (const float*)d_in[9];
  const float* bi = (const float*)d_in[10];
  const float* Wf = (const float*)d_in[11];
  const float* bf = (const float*)d_in[12];
  const float* Wo = (const float*)d_in[13];
  const float* bo = (const float*)d_in[14];
  const float* Rz = (const float*)d_in[15];
  const float* rbz = (const float*)d_in[16];
  const float* Ri = (const float*)d_in[17];
  const float* rbi = (const float*)d_in[18];
  const float* Rf = (const float*)d_in[19];
  const float* rbf = (const float*)d_in[20];
  const float* Ro = (const float*)d_in[21];
  const float* rbo = (const float*)d_in[22];
  float* out = (float*)d_out;

  char* ws = (char*)d_ws;
  __hip_bfloat16* xh2 = (__hip_bfloat16*)(ws);                       // 32 MiB
  __hip_bfloat16* xc2 = (__hip_bfloat16*)(ws + 33554432);            // 16 MiB
  __hip_bfloat16* WT2 = (__hip_bfloat16*)(ws + 33554432 + 16777216); // 16 MiB
  float* bias         = (float*)(ws + 33554432 + 2 * 16777216);      // 32 KiB

  prep_all<<<6152, 256, 0, stream>>>(
      x, h_prev, ln_g, ln_b, conv_w, conv_b, xh2, xc2,
      Wz, Wi, Wf, Wo, Rz, Ri, Rf, Ro, WT2,
      bz, bi, bf, bo, rbz, rbi, rbf, rbo, bias);
  gemm_fused<<<dim3(32, 8, 4), 512, 0, stream>>>(xh2, xc2, WT2, bias, c_prev, out);
}